// Round 4
// baseline (637.696 us; speedup 1.0000x reference)
//
#include <hip/hip_runtime.h>
#include <hip/hip_bf16.h>
#include <math.h>

// DecoderSphere B=16,T=65536,D=32. MFMA bf16, bpermute-based layout transform.
// D[feat][pt] = W^T * X^T; A = register-resident W^T frags; B built from the
// previous C-layout accumulators via 8 ds_bpermute + 4 cndmask (no LDS round
// trip, no barriers, no bank conflicts in the inner loop).

typedef __attribute__((ext_vector_type(8))) short short8;
typedef __attribute__((ext_vector_type(4))) float f32x4;

#define CFW 36   // cf row stride (dwords): 16B-aligned, even quad-bank spread

static __device__ __forceinline__ unsigned short f2bf(float x) {
    __hip_bfloat16 b = __float2bfloat16(x);
    unsigned short u;
    __builtin_memcpy(&u, &b, 2);
    return u;
}

// pack 2 floats to bf16x2, RNE (identical to __float2bfloat16 for finite vals)
static __device__ __forceinline__ unsigned pk2(float a, float b) {
    unsigned ua = __builtin_bit_cast(unsigned, a);
    unsigned ub = __builtin_bit_cast(unsigned, b);
    ua += 0x7fffu + ((ua >> 16) & 1u);
    ub += 0x7fffu + ((ub >> 16) & 1u);
    return __builtin_amdgcn_perm(ub, ua, 0x07060302);  // {hi16(ub),hi16(ua)}
}

// C-layout (x0=feats 16*0+4q+r, x1=feats 16*1+4q+r of pt m15) -> relu -> bf16
// -> B-frag (k=8q+j feats of pt m15). Pure intra-column redistribution.
static __device__ __forceinline__ short8 xform(const f32x4 x0, const f32x4 x1,
                                               int a01, int a23, bool hs) {
    const int p00 = (int)pk2(fmaxf(x0[0], 0.f), fmaxf(x0[1], 0.f));
    const int p01 = (int)pk2(fmaxf(x0[2], 0.f), fmaxf(x0[3], 0.f));
    const int p10 = (int)pk2(fmaxf(x1[0], 0.f), fmaxf(x1[1], 0.f));
    const int p11 = (int)pk2(fmaxf(x1[2], 0.f), fmaxf(x1[3], 0.f));
    const int s0a = __builtin_amdgcn_ds_bpermute(a01, p00);
    const int s0b = __builtin_amdgcn_ds_bpermute(a01, p10);
    const int s1a = __builtin_amdgcn_ds_bpermute(a01, p01);
    const int s1b = __builtin_amdgcn_ds_bpermute(a01, p11);
    const int s2a = __builtin_amdgcn_ds_bpermute(a23, p00);
    const int s2b = __builtin_amdgcn_ds_bpermute(a23, p10);
    const int s3a = __builtin_amdgcn_ds_bpermute(a23, p01);
    const int s3b = __builtin_amdgcn_ds_bpermute(a23, p11);
    int4 r;
    r.x = hs ? s0b : s0a;
    r.y = hs ? s1b : s1a;
    r.z = hs ? s2b : s2a;
    r.w = hs ? s3b : s3a;
    return __builtin_bit_cast(short8, r);
}

__global__ __launch_bounds__(256, 4) void decoder_mfma(
    const float* __restrict__ p,
    const float* __restrict__ c,
    const float* __restrict__ fc_p_w,
    const float* __restrict__ fc_p_b,
    const float* __restrict__ w0g,
    const float* __restrict__ b0g,
    const float* __restrict__ w1g,
    const float* __restrict__ b1g,
    const float* __restrict__ fc_out_w,
    const float* __restrict__ fc_out_b,
    float* __restrict__ out)
{
    __shared__ float lds[9728];   // 38912 B -> 4 blocks/CU
    const int tid  = threadIdx.x;
    const int wave = tid >> 6;
    const int lane = tid & 63;
    const int m15  = lane & 15;
    const int q    = lane >> 4;

    float* cfb = lds + wave * 2304;   // [64 pts][36] f32 cf, wave-private
    float* cb  = lds + 9216;          // constants [512]

    // ---- stage constants (once per block) ----
    // [0,96): fc_p_w [96,128): fc_p_b [128,288): b0 [288,448): b1
    // [448,480): fc_out_w [480]: fc_out_b
    for (int t = tid; t < 481; t += 256) {
        float v;
        if      (t < 96)  v = fc_p_w[t];
        else if (t < 128) v = fc_p_b[t - 96];
        else if (t < 288) v = b0g[t - 128];
        else if (t < 448) v = b1g[t - 288];
        else if (t < 480) v = fc_out_w[t - 448];
        else              v = fc_out_b[0];
        cb[t] = v;
    }

    // ---- register-resident W^T A-frags: A[m=lane&15][k=8q+j] = W[k][16h+m] ----
    short8 wf[5][2][2];
#pragma unroll
    for (int i = 0; i < 5; ++i) {
#pragma unroll
        for (int h = 0; h < 2; ++h) {
            const int base = i * 1024 + 16 * h + m15;
            short8 a0, a1;
#pragma unroll
            for (int j = 0; j < 8; ++j) {
                a0[j] = (short)f2bf(w0g[base + (8 * q + j) * 32]);
                a1[j] = (short)f2bf(w1g[base + (8 * q + j) * 32]);
            }
            wf[i][0][h] = a0;
            wf[i][1][h] = a1;
        }
    }

    __syncthreads();

    // ================= phase 1: per-lane interp =================
    const float PI_F = 3.1415927410125732f;
    const int g = blockIdx.x * 256 + tid;
    const int b = g >> 16;                      // T = 65536

    const float px = p[3 * g + 0];
    const float py = p[3 * g + 1];
    const float pz = p[3 * g + 2];

    const float lat = 90.0f - (atan2f(pz, sqrtf(px * px + py * py)) * 180.0f) / PI_F;
    const float mer = fmodf(360.0f + (atan2f(py, px) * 180.0f) / PI_F, 360.0f);

    const int xg = (int)floorf(mer / 5.625f);
    const int yg = (int)floorf(lat / 2.8125f);

    const int xl = (xg + 63) & 63;
    const int xr = (xg + 1) & 63;
    const int ylo = yg - 1 - ((yg - 1) >> 6);
    const int yhi = yg + 1 - ((yg + 1) >> 6);

    const float dx = (float)(xr - xg);
    const float dy = (float)(yhi - yg);

    const int yloi = ylo < 63 ? ylo : 63;
    const int yhii = yhi < 63 ? yhi : 63;

    const float w11 = dx * dy;
    const float w12 = (1.0f - dx) * dy;
    const float w21 = dx * (1.0f - dy);
    const float w22 = (1.0f - dx) * (1.0f - dy);

    const float* gb  = c + (size_t)b * (64 * 64 * 32);
    const float* r11 = gb + (xl * 64 + yloi) * 32;
    const float* r12 = gb + (xr * 64 + yloi) * 32;
    const float* r21 = gb + (xl * 64 + yhii) * 32;
    const float* r22 = gb + (xr * 64 + yhii) * 32;

    float* cfr = cfb + lane * CFW;
#pragma unroll
    for (int d = 0; d < 32; d += 4) {
        const f32x4 a  = *(const f32x4*)(r11 + d);
        const f32x4 e  = *(const f32x4*)(r12 + d);
        const f32x4 f  = *(const f32x4*)(r21 + d);
        const f32x4 h4 = *(const f32x4*)(r22 + d);
        f32x4 v = w11 * a + w12 * e + w21 * f + w22 * h4;
        *(f32x4*)(cfr + d) = v;
    }

    __builtin_amdgcn_wave_barrier();   // order phase-1 LDS writes before reads

    // ================= phase 2: 4 tiles of 16 points =================
    const int a01 = 4 * (m15 + 32 * (q & 1));   // bperm src for slots 0,1
    const int a23 = a01 + 64;                   // slots 2,3
    const bool hs = q >= 2;

    const int ipx = __builtin_bit_cast(int, px);
    const int ipy = __builtin_bit_cast(int, py);
    const int ipz = __builtin_bit_cast(int, pz);

#pragma unroll 1
    for (int t = 0; t < 4; ++t) {
        const int ptl = t * 16 + m15;
        const int ap  = 4 * ptl;
        const float qx = __builtin_bit_cast(float, __builtin_amdgcn_ds_bpermute(ap, ipx));
        const float qy = __builtin_bit_cast(float, __builtin_amdgcn_ds_bpermute(ap, ipy));
        const float qz = __builtin_bit_cast(float, __builtin_amdgcn_ds_bpermute(ap, ipz));

        f32x4 net[2], cf[2];
#pragma unroll
        for (int h = 0; h < 2; ++h) {
            const int fo = 16 * h + 4 * q;
            const f32x4 wx = *(const f32x4*)(cb + fo);
            const f32x4 wy = *(const f32x4*)(cb + 32 + fo);
            const f32x4 wz = *(const f32x4*)(cb + 64 + fo);
            const f32x4 bb = *(const f32x4*)(cb + 96 + fo);
            net[h] = qx * wx + qy * wy + qz * wz + bb;
            cf[h]  = *(const f32x4*)(cfb + ptl * CFW + fo);
        }

#pragma unroll
        for (int i = 0; i < 5; ++i) {
            net[0] += cf[0];
            net[1] += cf[1];

            const short8 xf = xform(net[0], net[1], a01, a23, hs);

            const int b0o = 128 + i * 32 + 4 * q;
            const f32x4 h0 = __builtin_amdgcn_mfma_f32_16x16x32_bf16(
                wf[i][0][0], xf, *(const f32x4*)(cb + b0o), 0, 0, 0);
            const f32x4 h1 = __builtin_amdgcn_mfma_f32_16x16x32_bf16(
                wf[i][0][1], xf, *(const f32x4*)(cb + b0o + 16), 0, 0, 0);

            const short8 hf = xform(h0, h1, a01, a23, hs);

            net[0] = __builtin_amdgcn_mfma_f32_16x16x32_bf16(wf[i][1][0], hf, net[0], 0, 0, 0);
            net[1] = __builtin_amdgcn_mfma_f32_16x16x32_bf16(wf[i][1][1], hf, net[1], 0, 0, 0);

            const int b1o = 288 + i * 32 + 4 * q;
            net[0] += *(const f32x4*)(cb + b1o);
            net[1] += *(const f32x4*)(cb + b1o + 16);
        }

        // epilogue: out[pt] = sum_f relu(net[f][pt]) * ow[f] + ob
        const f32x4 ow0 = *(const f32x4*)(cb + 448 + 4 * q);
        const f32x4 ow1 = *(const f32x4*)(cb + 448 + 16 + 4 * q);
        float s = 0.f;
#pragma unroll
        for (int r = 0; r < 4; ++r)
            s += fmaxf(net[0][r], 0.f) * ow0[r] + fmaxf(net[1][r], 0.f) * ow1[r];
        s += __shfl_xor(s, 16, 64);
        s += __shfl_xor(s, 32, 64);
        if (q == 0)
            out[blockIdx.x * 256 + wave * 64 + ptl] = s + cb[480];
    }
}

extern "C" void kernel_launch(void* const* d_in, const int* in_sizes, int n_in,
                              void* d_out, int out_size, void* d_ws, size_t ws_size,
                              hipStream_t stream) {
    const float* p        = (const float*)d_in[0];
    const float* c        = (const float*)d_in[2];
    const float* fc_p_w   = (const float*)d_in[4];
    const float* fc_p_b   = (const float*)d_in[5];
    const float* w0       = (const float*)d_in[6];
    const float* b0       = (const float*)d_in[7];
    const float* w1       = (const float*)d_in[8];
    const float* b1       = (const float*)d_in[9];
    const float* fc_out_w = (const float*)d_in[10];
    const float* fc_out_b = (const float*)d_in[11];
    float* out = (float*)d_out;

    dim3 block(256);
    dim3 grid((16 * 65536) / 256);   // 4096 blocks
    hipLaunchKernelGGL(decoder_mfma, grid, block, 0, stream,
                       p, c, fc_p_w, fc_p_b, w0, b0, w1, b1,
                       fc_out_w, fc_out_b, out);
}

// Round 5
// 214.541 us; speedup vs baseline: 2.9724x; 2.9724x over previous
//
#include <hip/hip_runtime.h>
#include <hip/hip_bf16.h>
#include <math.h>

// DecoderSphere B=16,T=65536,D=32. MFMA bf16, bpermute-based layout transform.
// D[feat][pt] = W^T * X^T; A = register-resident W^T frags; B built from the
// previous C-layout accumulators via 8 ds_bpermute + 4 cndmask (no LDS round
// trip, no barriers, no bank conflicts in the inner loop).
// launch_bounds(256,2): cap 256 VGPRs. (256,4) in R4 spilled the 80-VGPR wf
// array to scratch -> 2 GB of spill traffic. Do not tighten this again.

typedef __attribute__((ext_vector_type(8))) short short8;
typedef __attribute__((ext_vector_type(4))) float f32x4;

#define CFW 36   // cf row stride (dwords): 16B-aligned, odd-quad bank spread

static __device__ __forceinline__ unsigned short f2bf(float x) {
    __hip_bfloat16 b = __float2bfloat16(x);
    unsigned short u;
    __builtin_memcpy(&u, &b, 2);
    return u;
}

// pack 2 floats to bf16x2, RNE (identical to __float2bfloat16 for finite vals)
static __device__ __forceinline__ unsigned pk2(float a, float b) {
    unsigned ua = __builtin_bit_cast(unsigned, a);
    unsigned ub = __builtin_bit_cast(unsigned, b);
    ua += 0x7fffu + ((ua >> 16) & 1u);
    ub += 0x7fffu + ((ub >> 16) & 1u);
    return __builtin_amdgcn_perm(ub, ua, 0x07060302);  // {hi16(ub),hi16(ua)}
}

// C-layout (x0=feats 16*0+4q+r, x1=feats 16*1+4q+r of pt m15) -> relu -> bf16
// -> B-frag (k=8q+j feats of pt m15). Pure intra-column redistribution.
static __device__ __forceinline__ short8 xform(const f32x4 x0, const f32x4 x1,
                                               int a01, int a23, bool hs) {
    const int p00 = (int)pk2(fmaxf(x0[0], 0.f), fmaxf(x0[1], 0.f));
    const int p01 = (int)pk2(fmaxf(x0[2], 0.f), fmaxf(x0[3], 0.f));
    const int p10 = (int)pk2(fmaxf(x1[0], 0.f), fmaxf(x1[1], 0.f));
    const int p11 = (int)pk2(fmaxf(x1[2], 0.f), fmaxf(x1[3], 0.f));
    const int s0a = __builtin_amdgcn_ds_bpermute(a01, p00);
    const int s0b = __builtin_amdgcn_ds_bpermute(a01, p10);
    const int s1a = __builtin_amdgcn_ds_bpermute(a01, p01);
    const int s1b = __builtin_amdgcn_ds_bpermute(a01, p11);
    const int s2a = __builtin_amdgcn_ds_bpermute(a23, p00);
    const int s2b = __builtin_amdgcn_ds_bpermute(a23, p10);
    const int s3a = __builtin_amdgcn_ds_bpermute(a23, p01);
    const int s3b = __builtin_amdgcn_ds_bpermute(a23, p11);
    int4 r;
    r.x = hs ? s0b : s0a;
    r.y = hs ? s1b : s1a;
    r.z = hs ? s2b : s2a;
    r.w = hs ? s3b : s3a;
    return __builtin_bit_cast(short8, r);
}

__global__ __launch_bounds__(256, 2) void decoder_mfma(
    const float* __restrict__ p,
    const float* __restrict__ c,
    const float* __restrict__ fc_p_w,
    const float* __restrict__ fc_p_b,
    const float* __restrict__ w0g,
    const float* __restrict__ b0g,
    const float* __restrict__ w1g,
    const float* __restrict__ b1g,
    const float* __restrict__ fc_out_w,
    const float* __restrict__ fc_out_b,
    float* __restrict__ out)
{
    __shared__ float lds[9728];   // 38912 B
    const int tid  = threadIdx.x;
    const int wave = tid >> 6;
    const int lane = tid & 63;
    const int m15  = lane & 15;
    const int q    = lane >> 4;

    float* cfb = lds + wave * 2304;   // [64 pts][36] f32 cf, wave-private
    float* cb  = lds + 9216;          // constants [512]

    // ---- stage constants (once per block) ----
    // [0,96): fc_p_w [96,128): fc_p_b [128,288): b0 [288,448): b1
    // [448,480): fc_out_w [480]: fc_out_b
    for (int t = tid; t < 481; t += 256) {
        float v;
        if      (t < 96)  v = fc_p_w[t];
        else if (t < 128) v = fc_p_b[t - 96];
        else if (t < 288) v = b0g[t - 128];
        else if (t < 448) v = b1g[t - 288];
        else if (t < 480) v = fc_out_w[t - 448];
        else              v = fc_out_b[0];
        cb[t] = v;
    }

    // ---- register-resident W^T A-frags: A[m=lane&15][k=8q+j] = W[k][16h+m] ----
    short8 wf[5][2][2];
#pragma unroll
    for (int i = 0; i < 5; ++i) {
#pragma unroll
        for (int h = 0; h < 2; ++h) {
            const int base = i * 1024 + 16 * h + m15;
            short8 a0, a1;
#pragma unroll
            for (int j = 0; j < 8; ++j) {
                a0[j] = (short)f2bf(w0g[base + (8 * q + j) * 32]);
                a1[j] = (short)f2bf(w1g[base + (8 * q + j) * 32]);
            }
            wf[i][0][h] = a0;
            wf[i][1][h] = a1;
        }
    }

    __syncthreads();

    // ================= phase 1: per-lane interp =================
    const float PI_F = 3.1415927410125732f;
    const int g = blockIdx.x * 256 + tid;
    const int b = g >> 16;                      // T = 65536

    const float px = p[3 * g + 0];
    const float py = p[3 * g + 1];
    const float pz = p[3 * g + 2];

    const float lat = 90.0f - (atan2f(pz, sqrtf(px * px + py * py)) * 180.0f) / PI_F;
    const float mer = fmodf(360.0f + (atan2f(py, px) * 180.0f) / PI_F, 360.0f);

    const int xg = (int)floorf(mer / 5.625f);
    const int yg = (int)floorf(lat / 2.8125f);

    const int xl = (xg + 63) & 63;
    const int xr = (xg + 1) & 63;
    const int ylo = yg - 1 - ((yg - 1) >> 6);
    const int yhi = yg + 1 - ((yg + 1) >> 6);

    const float dx = (float)(xr - xg);
    const float dy = (float)(yhi - yg);

    const int yloi = ylo < 63 ? ylo : 63;
    const int yhii = yhi < 63 ? yhi : 63;

    const float w11 = dx * dy;
    const float w12 = (1.0f - dx) * dy;
    const float w21 = dx * (1.0f - dy);
    const float w22 = (1.0f - dx) * (1.0f - dy);

    const float* gb  = c + (size_t)b * (64 * 64 * 32);
    const float* r11 = gb + (xl * 64 + yloi) * 32;
    const float* r12 = gb + (xr * 64 + yloi) * 32;
    const float* r21 = gb + (xl * 64 + yhii) * 32;
    const float* r22 = gb + (xr * 64 + yhii) * 32;

    float* cfr = cfb + lane * CFW;
#pragma unroll
    for (int d = 0; d < 32; d += 4) {
        const f32x4 a  = *(const f32x4*)(r11 + d);
        const f32x4 e  = *(const f32x4*)(r12 + d);
        const f32x4 f  = *(const f32x4*)(r21 + d);
        const f32x4 h4 = *(const f32x4*)(r22 + d);
        f32x4 v = w11 * a + w12 * e + w21 * f + w22 * h4;
        *(f32x4*)(cfr + d) = v;
    }

    __builtin_amdgcn_wave_barrier();   // order phase-1 LDS writes before reads

    // ================= phase 2: 4 tiles of 16 points =================
    const int a01 = 4 * (m15 + 32 * (q & 1));   // bperm src for slots 0,1
    const int a23 = a01 + 64;                   // slots 2,3
    const bool hs = q >= 2;

    const int ipx = __builtin_bit_cast(int, px);
    const int ipy = __builtin_bit_cast(int, py);
    const int ipz = __builtin_bit_cast(int, pz);

#pragma unroll 1
    for (int t = 0; t < 4; ++t) {
        const int ptl = t * 16 + m15;
        const int ap  = 4 * ptl;
        const float qx = __builtin_bit_cast(float, __builtin_amdgcn_ds_bpermute(ap, ipx));
        const float qy = __builtin_bit_cast(float, __builtin_amdgcn_ds_bpermute(ap, ipy));
        const float qz = __builtin_bit_cast(float, __builtin_amdgcn_ds_bpermute(ap, ipz));

        f32x4 net[2], cf[2];
#pragma unroll
        for (int h = 0; h < 2; ++h) {
            const int fo = 16 * h + 4 * q;
            const f32x4 wx = *(const f32x4*)(cb + fo);
            const f32x4 wy = *(const f32x4*)(cb + 32 + fo);
            const f32x4 wz = *(const f32x4*)(cb + 64 + fo);
            const f32x4 bb = *(const f32x4*)(cb + 96 + fo);
            net[h] = qx * wx + qy * wy + qz * wz + bb;
            cf[h]  = *(const f32x4*)(cfb + ptl * CFW + fo);
        }

#pragma unroll
        for (int i = 0; i < 5; ++i) {
            net[0] += cf[0];
            net[1] += cf[1];

            const short8 xf = xform(net[0], net[1], a01, a23, hs);

            const int b0o = 128 + i * 32 + 4 * q;
            const f32x4 h0 = __builtin_amdgcn_mfma_f32_16x16x32_bf16(
                wf[i][0][0], xf, *(const f32x4*)(cb + b0o), 0, 0, 0);
            const f32x4 h1 = __builtin_amdgcn_mfma_f32_16x16x32_bf16(
                wf[i][0][1], xf, *(const f32x4*)(cb + b0o + 16), 0, 0, 0);

            const short8 hf = xform(h0, h1, a01, a23, hs);

            net[0] = __builtin_amdgcn_mfma_f32_16x16x32_bf16(wf[i][1][0], hf, net[0], 0, 0, 0);
            net[1] = __builtin_amdgcn_mfma_f32_16x16x32_bf16(wf[i][1][1], hf, net[1], 0, 0, 0);

            const int b1o = 288 + i * 32 + 4 * q;
            net[0] += *(const f32x4*)(cb + b1o);
            net[1] += *(const f32x4*)(cb + b1o + 16);
        }

        // epilogue: out[pt] = sum_f relu(net[f][pt]) * ow[f] + ob
        const f32x4 ow0 = *(const f32x4*)(cb + 448 + 4 * q);
        const f32x4 ow1 = *(const f32x4*)(cb + 448 + 16 + 4 * q);
        float s = 0.f;
#pragma unroll
        for (int r = 0; r < 4; ++r)
            s += fmaxf(net[0][r], 0.f) * ow0[r] + fmaxf(net[1][r], 0.f) * ow1[r];
        s += __shfl_xor(s, 16, 64);
        s += __shfl_xor(s, 32, 64);
        if (q == 0)
            out[blockIdx.x * 256 + wave * 64 + ptl] = s + cb[480];
    }
}

extern "C" void kernel_launch(void* const* d_in, const int* in_sizes, int n_in,
                              void* d_out, int out_size, void* d_ws, size_t ws_size,
                              hipStream_t stream) {
    const float* p        = (const float*)d_in[0];
    const float* c        = (const float*)d_in[2];
    const float* fc_p_w   = (const float*)d_in[4];
    const float* fc_p_b   = (const float*)d_in[5];
    const float* w0       = (const float*)d_in[6];
    const float* b0       = (const float*)d_in[7];
    const float* w1       = (const float*)d_in[8];
    const float* b1       = (const float*)d_in[9];
    const float* fc_out_w = (const float*)d_in[10];
    const float* fc_out_b = (const float*)d_in[11];
    float* out = (float*)d_out;

    dim3 block(256);
    dim3 grid((16 * 65536) / 256);   // 4096 blocks
    hipLaunchKernelGGL(decoder_mfma, grid, block, 0, stream,
                       p, c, fc_p_w, fc_p_b, w0, b0, w1, b1,
                       fc_out_w, fc_out_b, out);
}